// Round 4
// baseline (354.540 us; speedup 1.0000x reference)
//
#include <hip/hip_runtime.h>
#include <hip/hip_bf16.h>

typedef __attribute__((ext_vector_type(8))) short bf16x8;
typedef __attribute__((ext_vector_type(4))) float f32x4;

#define NB    8
#define ND1   16
#define NN    2048
#define NF    64
#define GN    1024

__device__ static inline ushort f2bf(float f) {
    unsigned int u = __builtin_bit_cast(unsigned int, f);
    unsigned int r = (u + 0x7FFFu + ((u >> 16) & 1u)) >> 16;
    return (ushort)r;
}

__device__ static inline void gload_lds16(const void* g, void* l) {
    __builtin_amdgcn_global_load_lds(
        (const __attribute__((address_space(1))) void*)g,
        (__attribute__((address_space(3))) void*)l, 16, 0, 0);
}

// ---------------------------------------------------------------------------
// prep_kernel: fused  (a) adj fp32->bf16  (b) support_T = (x@W)^T in bf16.
// Blocks [0,2048): conv role. Blocks [2048, 6144): support role.
// ---------------------------------------------------------------------------
__global__ __launch_bounds__(256) void prep_kernel(
    const float* __restrict__ x, const float* __restrict__ w,
    const float* __restrict__ adj, ushort* __restrict__ sT,
    ushort* __restrict__ adjb)
{
    __shared__ __align__(16) char smem[16384 + 16640];  // Ws | xs (tr aliases xs)
    int t = threadIdx.x;

    if (blockIdx.x < 2048) {
        // ---- conv role: 32B/lane loads, 16B stores, 8 grid-stride iters ----
        int idx = blockIdx.x * 256 + t;
        const int stride = 2048 * 256;
        const float4* a4 = (const float4*)adj;
        uint4* o4 = (uint4*)adjb;
        const int n8 = NB * NN * NN / 8;
        for (int i = idx; i < n8; i += stride) {
            float4 v0 = a4[2 * i];
            float4 v1 = a4[2 * i + 1];
            union { uint4 q; ushort u[8]; } p;
            p.u[0] = f2bf(v0.x); p.u[1] = f2bf(v0.y);
            p.u[2] = f2bf(v0.z); p.u[3] = f2bf(v0.w);
            p.u[4] = f2bf(v1.x); p.u[5] = f2bf(v1.y);
            p.u[6] = f2bf(v1.z); p.u[7] = f2bf(v1.w);
            o4[i] = p.q;
        }
        return;
    }

    // ---- support role ----
    float*  Ws = (float*)smem;
    float*  xs = (float*)(smem + 16384);
    ushort* tr = (ushort*)(smem + 16384);   // aliases xs (barrier-separated)

    int bid = blockIdx.x - 2048;
    int b  = bid >> 9;
    int r  = bid & 511;
    int i  = r >> 5;
    int mb = r & 31;

    const float4* w4 = (const float4*)w;
    const float4* x4 = (const float4*)(x + (((size_t)(b * ND1 + i)) * NN + mb * 64) * NF);
#pragma unroll
    for (int j = 0; j < 4; ++j) {
        float4 wv = w4[j * 256 + t];
        int fl = j * 1024 + t * 4;
        Ws[fl + 0] = wv.x; Ws[fl + 1] = wv.y; Ws[fl + 2] = wv.z; Ws[fl + 3] = wv.w;
        float4 xv = x4[j * 256 + t];
        int ml = fl >> 6, f = fl & 63;
        float* xr = &xs[ml * 65 + f];
        xr[0] = xv.x; xr[1] = xv.y; xr[2] = xv.z; xr[3] = xv.w;
    }
    __syncthreads();

    int ml = t & 63;
    int g0 = (t >> 6) * 16;
    f32x4 acc4[4] = {0.f, 0.f, 0.f, 0.f};
    for (int f = 0; f < 64; ++f) {
        float xv = xs[ml * 65 + f];
        const f32x4* wp = (const f32x4*)&Ws[f * 64 + g0];
#pragma unroll
        for (int q = 0; q < 4; ++q) acc4[q] += xv * wp[q];
    }
    __syncthreads();   // xs reads done before tr (alias) writes
#pragma unroll
    for (int j = 0; j < 16; ++j)
        tr[(g0 + j) * 72 + ml] = f2bf(acc4[j >> 2][j & 3]);
    __syncthreads();

    int g = t >> 2, part = t & 3;
    const uint4* src = (const uint4*)&tr[g * 72 + part * 16];
    uint4* dst = (uint4*)(sT + ((size_t)(b * GN + i * 64 + g)) * NN + mb * 64 + part * 16);
    dst[0] = src[0];
    dst[1] = src[1];
}

// ---------------------------------------------------------------------------
// gemm8_kernel: 8-phase 256x256 tile, BK=64 as 2 K-halves, 2 dbuf, 128 KiB.
// Per K-tile: 4 phases {ds_read subtile, stage 1 half, bar, lgkm0, setprio,
// 16 MFMA, setprio, [vmcnt(8)], bar}. Stage ring (K-half granularity):
//   P1: A(t+1,ks1)  P2: B(t+1,ks1)  P3: A(t+2,ks0)  P4: B(t+2,ks0)
// Waits: vmcnt(8) before P3-reads and before next tile's P1-reads.
// LDS region (ushort idx): buf*32768 + op*16384 + ks*8192; within region,
// stripe(16 rows)*512 + (kg*16 + r)*8  -> conflict-free b128 frag reads.
// ---------------------------------------------------------------------------
__global__ __launch_bounds__(512, 2) void gemm8_kernel(
    const ushort* __restrict__ adjb,
    const ushort* __restrict__ sT,
    float* __restrict__ out)
{
    __shared__ __align__(16) ushort lds[65536];  // 128 KiB

    const int t    = threadIdx.x;
    const int lane = t & 63;
    const int w    = t >> 6;
    const int wm   = w >> 2;
    const int wn   = w & 3;

    int bid  = blockIdx.x;
    int tile = (bid & 7) * 32 + (bid >> 3);   // XCD k owns batch k
    int b    = tile >> 5;
    int r    = tile & 31;
    int n0   = (r >> 2) * 256;
    int c0   = (r & 3) * 256;

    const ushort* Ab = adjb + (size_t)b * NN * NN + (size_t)n0 * NN;
    const ushort* Bb = sT   + (size_t)b * GN * NN + (size_t)c0 * NN;

    const int rS  = lane & 15;
    const int cgS = lane >> 4;
    const int fq  = ((lane >> 4) * 16 + (lane & 15)) * 8;

    f32x4 acc[8][4];
#pragma unroll
    for (int a = 0; a < 8; ++a)
#pragma unroll
        for (int c = 0; c < 4; ++c) acc[a][c] = (f32x4){0.f, 0.f, 0.f, 0.f};

    // stage one 16KB K-half: 2 gloads (stripes 2w, 2w+1)
    auto stg = [&](const ushort* __restrict__ srcb, int tt, int ks, int regionUS) {
#pragma unroll
        for (int j = 0; j < 2; ++j) {
            gload_lds16(srcb + (size_t)((2 * w + j) * 16 + rS) * NN + tt * 64 + ks * 32 + cgS * 8,
                        &lds[regionUS + (2 * w + j) * 512 + lane * 8]);
        }
    };

#define FRAG_A(Ac_, ksoff, ah)                                                  \
    _Pragma("unroll")                                                           \
    for (int a_ = 0; a_ < 4; ++a_)                                              \
        af[a_] = *(const bf16x8*)&lds[(Ac_) + (ksoff) + (wm * 8 + (ah) * 4 + a_) * 512 + fq];
#define FRAG_B(Bc_, ksoff)                                                      \
    _Pragma("unroll")                                                           \
    for (int c_ = 0; c_ < 4; ++c_)                                              \
        bfv[c_] = *(const bf16x8*)&lds[(Bc_) + (ksoff) + (wn * 4 + c_) * 512 + fq];
#define MFMA16(aoff)                                                            \
    __builtin_amdgcn_s_setprio(1);                                              \
    _Pragma("unroll")                                                           \
    for (int a_ = 0; a_ < 4; ++a_)                                              \
        _Pragma("unroll")                                                       \
        for (int c_ = 0; c_ < 4; ++c_)                                          \
            acc[(aoff) + a_][c_] = __builtin_amdgcn_mfma_f32_16x16x32_bf16(     \
                af[a_], bfv[c_], acc[(aoff) + a_][c_], 0, 0, 0);                \
    __builtin_amdgcn_s_setprio(0);
#define BAR() __builtin_amdgcn_s_barrier()
#define LGKM0() asm volatile("s_waitcnt lgkmcnt(0)" ::: "memory")

#define TILE(tt, S12, S34, W2A, W1A)                                            \
    {                                                                           \
        const int buf_ = (tt) & 1;                                              \
        const int Ac = buf_ * 32768, Bc = Ac + 16384;                           \
        const int An = (buf_ ^ 1) * 32768, Bn = An + 16384;                     \
        bf16x8 af[4], bfv[4];                                                   \
        /* P1: ks0, a-half0 + B(ks0) */                                         \
        FRAG_A(Ac, 0, 0); FRAG_B(Bc, 0);                                        \
        if (S12) stg(Ab, (tt) + 1, 1, An + 8192);                               \
        BAR(); LGKM0(); MFMA16(0); BAR();                                       \
        /* P2: ks0, a-half1 (B reused) */                                       \
        FRAG_A(Ac, 0, 1);                                                       \
        if (S12) stg(Bb, (tt) + 1, 1, Bn + 8192);                               \
        BAR(); LGKM0(); MFMA16(4);                                              \
        asm volatile(W2A ::: "memory"); BAR();                                  \
        /* P3: ks1, a-half0 + B(ks1) */                                         \
        FRAG_A(Ac, 8192, 0); FRAG_B(Bc, 8192);                                  \
        if (S34) stg(Ab, (tt) + 2, 0, Ac);                                      \
        BAR(); LGKM0(); MFMA16(0); BAR();                                       \
        /* P4: ks1, a-half1 */                                                  \
        FRAG_A(Ac, 8192, 1);                                                    \
        if (S34) stg(Bb, (tt) + 2, 0, Bc);                                      \
        BAR(); LGKM0(); MFMA16(4);                                              \
        asm volatile(W1A ::: "memory"); BAR();                                  \
    }

    // prologue: A(0,0) B(0,0) A(0,1) B(0,1) A(1,0) B(1,0); wait first pair
    stg(Ab, 0, 0, 0);
    stg(Bb, 0, 0, 16384);
    stg(Ab, 0, 1, 8192);
    stg(Bb, 0, 1, 24576);
    stg(Ab, 1, 0, 32768);
    stg(Bb, 1, 0, 49152);
    asm volatile("s_waitcnt vmcnt(8)" ::: "memory");
    BAR();

    for (int tt = 0; tt < 30; ++tt)
        TILE(tt, 1, 1, "s_waitcnt vmcnt(8)", "s_waitcnt vmcnt(8)");
    TILE(30, 1, 0, "s_waitcnt vmcnt(8)", "s_waitcnt vmcnt(4)");
    TILE(31, 0, 0, "s_waitcnt vmcnt(0)", "");

    // ---- epilogue ----
#pragma unroll
    for (int a = 0; a < 8; ++a) {
        int row0 = n0 + wm * 128 + a * 16 + (lane >> 4) * 4;
#pragma unroll
        for (int c = 0; c < 4; ++c) {
            int col = c0 + wn * 64 + c * 16 + (lane & 15);
            int ii = col >> 6, g = col & 63;
            float* op = out + (((size_t)(b * ND1 + ii)) * NN + row0) * NF + g;
#pragma unroll
            for (int e = 0; e < 4; ++e)
                op[e * NF] = acc[a][c][e];
        }
    }
}

// ---------------------------------------------------------------------------
// Fallback path (ws too small for adjb): support-only + reg-staged GEMM
// ---------------------------------------------------------------------------
__global__ __launch_bounds__(256) void support_kernel(
    const float* __restrict__ x, const float* __restrict__ w,
    ushort* __restrict__ sT)
{
    __shared__ __align__(16) float Ws[64 * 64];
    __shared__ __align__(16) float xs[64 * 65];
    __shared__ __align__(16) ushort tr[64 * 72];

    int t = threadIdx.x;
    int bid = blockIdx.x;
    int b  = bid >> 9;
    int r  = bid & 511;
    int i  = r >> 5;
    int mb = r & 31;

    const float4* w4 = (const float4*)w;
    const float4* x4 = (const float4*)(x + (((size_t)(b * ND1 + i)) * NN + mb * 64) * NF);
#pragma unroll
    for (int j = 0; j < 4; ++j) {
        float4 wv = w4[j * 256 + t];
        int fl = j * 1024 + t * 4;
        Ws[fl + 0] = wv.x; Ws[fl + 1] = wv.y; Ws[fl + 2] = wv.z; Ws[fl + 3] = wv.w;
        float4 xv = x4[j * 256 + t];
        int ml = fl >> 6, f = fl & 63;
        float* xr = &xs[ml * 65 + f];
        xr[0] = xv.x; xr[1] = xv.y; xr[2] = xv.z; xr[3] = xv.w;
    }
    __syncthreads();

    int ml = t & 63;
    int g0 = (t >> 6) * 16;
    f32x4 acc4[4] = {0.f, 0.f, 0.f, 0.f};
    for (int f = 0; f < 64; ++f) {
        float xv = xs[ml * 65 + f];
        const f32x4* wp = (const f32x4*)&Ws[f * 64 + g0];
#pragma unroll
        for (int q = 0; q < 4; ++q) acc4[q] += xv * wp[q];
    }
#pragma unroll
    for (int j = 0; j < 16; ++j)
        tr[(g0 + j) * 72 + ml] = f2bf(acc4[j >> 2][j & 3]);
    __syncthreads();

    int g = t >> 2, part = t & 3;
    const uint4* src = (const uint4*)&tr[g * 72 + part * 16];
    uint4* dst = (uint4*)(sT + ((size_t)(b * GN + i * 64 + g)) * NN + mb * 64 + part * 16);
    dst[0] = src[0];
    dst[1] = src[1];
}

__global__ __launch_bounds__(256) void gcn_gemm_fb_kernel(
    const float* __restrict__ adjf, const ushort* __restrict__ sT,
    float* __restrict__ out)
{
    __shared__ __align__(16) ushort lA[128 * 64];
    __shared__ __align__(16) ushort lB[128 * 64];

    int t = threadIdx.x;
    int bid0 = blockIdx.x;
    int bid = (bid0 & 7) * 128 + (bid0 >> 3);
    int b  = bid >> 7;
    int rr = bid & 127;
    int n0 = (rr >> 3) * 128;
    int c0 = (rr & 7) * 128;

    const float*  Af = adjf + (size_t)b * NN * NN;
    const ushort* Bb = sT + (size_t)b * GN * NN;

    int lane = t & 63, wv = t >> 6;
    int wr = (wv >> 1) * 64, wc = (wv & 1) * 64;

    f32x4 acc[4][4];
#pragma unroll
    for (int a = 0; a < 4; ++a)
#pragma unroll
        for (int c = 0; c < 4; ++c) acc[a][c] = (f32x4){0.f, 0.f, 0.f, 0.f};

    int sRow = t >> 3;
    int sCol = (t & 7) * 8;

    for (int k0 = 0; k0 < NN; k0 += 64) {
#pragma unroll
        for (int i = 0; i < 4; ++i) {
            const float* src = Af + (size_t)(n0 + i * 32 + sRow) * NN + k0 + sCol;
            float4 v0 = *(const float4*)src;
            float4 v1 = *(const float4*)(src + 4);
            union { bf16x8 v; ushort u[8]; } p;
            p.u[0] = f2bf(v0.x); p.u[1] = f2bf(v0.y);
            p.u[2] = f2bf(v0.z); p.u[3] = f2bf(v0.w);
            p.u[4] = f2bf(v1.x); p.u[5] = f2bf(v1.y);
            p.u[6] = f2bf(v1.z); p.u[7] = f2bf(v1.w);
            *(bf16x8*)&lA[(i * 32 + sRow) * 64 + sCol] = p.v;
        }
#pragma unroll
        for (int i = 0; i < 4; ++i)
            gload_lds16(Bb + (size_t)(c0 + i * 32 + sRow) * NN + k0 + sCol,
                        &lB[(i * 32 + sRow) * 64 + sCol]);
        __syncthreads();
#pragma unroll
        for (int kk = 0; kk < 2; ++kk) {
            bf16x8 af[4], bfr[4];
#pragma unroll
            for (int a = 0; a < 4; ++a)
                af[a] = *(const bf16x8*)&lA[(wr + a * 16 + (lane & 15)) * 64 + kk * 32 + (lane >> 4) * 8];
#pragma unroll
            for (int c = 0; c < 4; ++c)
                bfr[c] = *(const bf16x8*)&lB[(wc + c * 16 + (lane & 15)) * 64 + kk * 32 + (lane >> 4) * 8];
#pragma unroll
            for (int a = 0; a < 4; ++a)
#pragma unroll
                for (int c = 0; c < 4; ++c)
                    acc[a][c] = __builtin_amdgcn_mfma_f32_16x16x32_bf16(af[a], bfr[c], acc[a][c], 0, 0, 0);
        }
        __syncthreads();
    }
#pragma unroll
    for (int a = 0; a < 4; ++a) {
        int row0 = n0 + wr + a * 16 + (lane >> 4) * 4;
#pragma unroll
        for (int c = 0; c < 4; ++c) {
            int col = c0 + wc + c * 16 + (lane & 15);
            int ii = col >> 6, g = col & 63;
            float* op = out + (((size_t)(b * ND1 + ii)) * NN + row0) * NF + g;
#pragma unroll
            for (int e = 0; e < 4; ++e)
                op[e * NF] = acc[a][c][e];
        }
    }
}

// ---------------------------------------------------------------------------
extern "C" void kernel_launch(void* const* d_in, const int* in_sizes, int n_in,
                              void* d_out, int out_size, void* d_ws, size_t ws_size,
                              hipStream_t stream) {
    const float* x   = (const float*)d_in[0];
    const float* adj = (const float*)d_in[1];
    const float* w   = (const float*)d_in[2];
    float* out = (float*)d_out;

    ushort* sT   = (ushort*)d_ws;
    ushort* adjb = (ushort*)((char*)d_ws + 33554432);
    bool preconv = ws_size >= (size_t)100663296;

    if (preconv) {
        prep_kernel<<<dim3(6144), dim3(256), 0, stream>>>(x, w, adj, sT, adjb);
        gemm8_kernel<<<dim3(256), dim3(512), 0, stream>>>(adjb, sT, out);
    } else {
        support_kernel<<<dim3(NB * ND1 * (NN / 64)), dim3(256), 0, stream>>>(x, w, sT);
        gcn_gemm_fb_kernel<<<dim3(NB * 16 * 8), dim3(256), 0, stream>>>(adj, sT, out);
    }
}